// Round 8
// baseline (484.407 us; speedup 1.0000x reference)
//
#include <hip/hip_runtime.h>

// B=2, L=128, E=1024, H=16, G=8, D=64, R=2. rows rr = b*128+i in [0,256).
// All inputs/outputs float32.
// R8: LDS-staged coalesced loads (scattered direct reads capped DRAM ~1 TB/s).
// R9/R11 lessons: stats must be slice-deduped; >=8 independent blocks/CU
//   needed for stage/compute overlap; never drop below 1024 blocks.
// R12 (WIN, 506->470): k_dotp split over e, 2048 blocks, 13 KB LDS, partials
//   combined in k_attn_p. Pattern: small tiles + many blocks + split-reduce.
// R13: apply same pattern to k_wun: split over j (2 halves) -> grid
//   (4 es, 2 jh, 256 rr) = 2048 blocks, 20 KB LDS, 8 blk/CU. Raw partials
//   w0/w1; LN-affine folded into k_qv staging. k_zero->1024 blocks.

// ---------------------------------------------------------------------------
// K0: seed biases / zeros. grid (256 rr, 4 qy), 256 thr.
__global__ __launch_bounds__(256) void k_zero(
    const float* __restrict__ bq, const float* __restrict__ bk, const float* __restrict__ bv,
    const float* __restrict__ bo,
    float* __restrict__ q_ws, float* __restrict__ k_ws, float* __restrict__ v_ws,
    float* __restrict__ qv_ws, float* __restrict__ out, float* __restrict__ Gu_ws)
{
  int rr = blockIdx.x, qy = blockIdx.y, tid = threadIdx.x;
  int i = qy * 256 + tid;
  q_ws[rr * 1024 + i] = bq[i];
  qv_ws[rr * 1024 + i] = 0.f;
  out[rr * 1024 + i] = bo[i];
  if (qy < 2) {
    k_ws[rr * 512 + i] = bk[i];
    v_ws[rr * 512 + i] = bv[i];
  }
  if (qy == 0) {
    int t = rr * 256 + tid;
    if (t < 4096) Gu_ws[t] = 0.f;
  }
}

// ---------------------------------------------------------------------------
// K1: q/k/v projections. grid (8 ct, 32 rt, 4 es) = 1024 blocks, 256 thr.
__global__ __launch_bounds__(256) void k_qkv(
    const float* __restrict__ Q, const float* __restrict__ K, const float* __restrict__ V,
    const float* __restrict__ Wq, const float* __restrict__ Wk, const float* __restrict__ Wv,
    float* __restrict__ q_ws, float* __restrict__ k_ws, float* __restrict__ v_ws)
{
  __shared__ float xs[8][256];  // 8 KB
  int ct = blockIdx.x, rt = blockIdx.y, es = blockIdx.z, tid = threadIdx.x;
  const float* X; const float* W; float* out; int ldW, ldO, c0;
  if (ct < 4)      { X = Q; W = Wq; out = q_ws; ldW = 1024; ldO = 1024; c0 = ct * 256; }
  else if (ct < 6) { X = K; W = Wk; out = k_ws; ldW = 512;  ldO = 512;  c0 = (ct - 4) * 256; }
  else             { X = V; W = Wv; out = v_ws; ldW = 512;  ldO = 512;  c0 = (ct - 6) * 256; }
  int row0 = rt * 8, e0 = es * 256;
  for (int f = tid; f < 512; f += 256) {
    int r = f >> 6, e4 = f & 63;
    *(float4*)&xs[r][e4 * 4] = *(const float4*)(X + (size_t)(row0 + r) * 1024 + e0 + e4 * 4);
  }
  __syncthreads();
  int cg = tid & 63, rs = tid >> 6;
  int c = c0 + cg * 4;
  const float* wp = W + (size_t)e0 * ldW + c;
  float a0[4] = {0, 0, 0, 0}, a1[4] = {0, 0, 0, 0};
  float4 wc = *(const float4*)wp;
  for (int e = 0; e < 256; e++) {
    int en = e + 1 < 256 ? e + 1 : 255;
    float4 wn = *(const float4*)(wp + (size_t)en * ldW);
    float x0 = xs[rs][e], x1 = xs[rs + 4][e];
    a0[0] += x0 * wc.x; a0[1] += x0 * wc.y; a0[2] += x0 * wc.z; a0[3] += x0 * wc.w;
    a1[0] += x1 * wc.x; a1[1] += x1 * wc.y; a1[2] += x1 * wc.z; a1[3] += x1 * wc.w;
    wc = wn;
  }
#pragma unroll
  for (int s = 0; s < 4; s++) {
    atomicAdd(out + (size_t)(row0 + rs) * ldO + c + s, a0[s]);
    atomicAdd(out + (size_t)(row0 + rs + 4) * ldO + c + s, a1[s]);
  }
}

// ---------------------------------------------------------------------------
// K2: S0[r,h] = (q[r,h,:].(k[r,g,:]+brk[g,:])) / 8  (Bu added by k_uproj)
// grid 32, 128 thr.
__global__ __launch_bounds__(128) void k_base(
    const float* __restrict__ q_ws, const float* __restrict__ k_ws,
    const float* __restrict__ brk, float* __restrict__ S0_ws)
{
  int t = blockIdx.x * 128 + threadIdx.x;  // 4096
  int r = t >> 4, h = t & 15, g = h >> 1;
  const float* qp = q_ws + r * 1024 + h * 64;
  const float* kp = k_ws + r * 512 + g * 64;
  const float* bp = brk + g * 64;
  float s = 0.f;
#pragma unroll
  for (int d4 = 0; d4 < 16; d4++) {
    float4 q4 = *(const float4*)(qp + d4 * 4);
    float4 k4 = *(const float4*)(kp + d4 * 4);
    float4 b4 = *(const float4*)(bp + d4 * 4);
    s += q4.x * (k4.x + b4.x) + q4.y * (k4.y + b4.y)
       + q4.z * (k4.z + b4.z) + q4.w * (k4.w + b4.w);
  }
  S0_ws[t] = s * 0.125f;
}

// ---------------------------------------------------------------------------
// K3: ut[rr][e][h] = 0.125 * sum_d q[rr,h*64+d] * Wrk[e, g*64+d], g=h>>1.
// grid (8 et, 16 rrt, 8 g) = 1024 blocks, 256 thr.
__global__ __launch_bounds__(256) void k_uproj(
    const float* __restrict__ q_ws, const float* __restrict__ Wrk,
    const float* __restrict__ lng, const float* __restrict__ lnb,
    float* __restrict__ ut_ws, float* __restrict__ Gu_ws, float* __restrict__ S0_ws)
{
  __shared__ float wt[64][128];  // [d][e_l] 32 KB
  __shared__ float qs[32][64];   // [m][d]   8 KB
  int et = blockIdx.x, rrt = blockIdx.y, g = blockIdx.z, tid = threadIdx.x;
  int e0 = et * 128, rr0 = rrt * 16;
  for (int f = tid; f < 2048; f += 256) {
    int er = f >> 4, dq = f & 15;
    float4 p = *(const float4*)(Wrk + (size_t)(e0 + er) * 512 + g * 64 + dq * 4);
    wt[dq * 4 + 0][er] = p.x; wt[dq * 4 + 1][er] = p.y;
    wt[dq * 4 + 2][er] = p.z; wt[dq * 4 + 3][er] = p.w;
  }
  for (int f = tid; f < 512; f += 256) {
    int m = f >> 4, dq = f & 15;
    int rr = rr0 + (m >> 1), h = g * 2 + (m & 1);
    float4 p = *(const float4*)(q_ws + (size_t)rr * 1024 + h * 64 + dq * 4);
    qs[m][dq * 4 + 0] = p.x; qs[m][dq * 4 + 1] = p.y;
    qs[m][dq * 4 + 2] = p.z; qs[m][dq * 4 + 3] = p.w;
  }
  __syncthreads();
  int eg = tid & 31, rs = tid >> 5;   // thread: 4 m (rs*4+i) x 4 e (eg*4+s)
  float acc[4][4];
#pragma unroll
  for (int i = 0; i < 4; i++)
#pragma unroll
    for (int s = 0; s < 4; s++) acc[i][s] = 0.f;
  for (int d = 0; d < 64; d++) {
    float4 wv = *(float4*)&wt[d][eg * 4];
#pragma unroll
    for (int i = 0; i < 4; i++) {
      float qv = qs[rs * 4 + i][d];
      acc[i][0] += qv * wv.x; acc[i][1] += qv * wv.y;
      acc[i][2] += qv * wv.z; acc[i][3] += qv * wv.w;
    }
  }
#pragma unroll
  for (int k = 0; k < 2; k++) {
    int rr = rr0 + rs * 2 + k;
#pragma unroll
    for (int s = 0; s < 4; s++) {
      int e = e0 + eg * 4 + s;
      float2 st;
      st.x = acc[2 * k][s] * 0.125f;
      st.y = acc[2 * k + 1][s] * 0.125f;
      *(float2*)(ut_ws + ((size_t)rr * 1024 + e) * 16 + g * 2) = st;
    }
  }
  float4 ge4 = *(const float4*)(lng + e0 + eg * 4);
  float4 be4 = *(const float4*)(lnb + e0 + eg * 4);
#pragma unroll
  for (int i = 0; i < 4; i++) {
    float pg = 0.125f * (ge4.x * acc[i][0] + ge4.y * acc[i][1] + ge4.z * acc[i][2] + ge4.w * acc[i][3]);
    float pb = 0.125f * (be4.x * acc[i][0] + be4.y * acc[i][1] + be4.z * acc[i][2] + be4.w * acc[i][3]);
#pragma unroll
    for (int mk = 16; mk >= 1; mk >>= 1) { pg += __shfl_xor(pg, mk); pb += __shfl_xor(pb, mk); }
    if (eg == 0) {
      int m = rs * 4 + i;
      int rr = rr0 + (m >> 1), h = g * 2 + (m & 1);
      atomicAdd(Gu_ws + rr * 16 + h, pg);
      atomicAdd(S0_ws + rr * 16 + h, pb);
    }
  }
}

// ---------------------------------------------------------------------------
// K4: PARTIAL scores. grid (4 jt, 256 rr, 2 et) = 2048 blocks, 128 thr.
// (unchanged from R12 — the win)
__global__ __launch_bounds__(128) void k_dotp(
    const float* __restrict__ rpe, const float* __restrict__ lng,
    const float* __restrict__ ut_ws,
    float* __restrict__ sraw0, float* __restrict__ sraw1,
    float* __restrict__ sxp0, float* __restrict__ sxp1,
    float* __restrict__ sqp0, float* __restrict__ sqp1)
{
  __shared__ float xs[32][68];    // 8.5 KB
  __shared__ float us_t[16][68];  // 4.25 KB
  int jt = blockIdx.x, rr = blockIdx.y, et = blockIdx.z, tid = threadIdx.x;
  int hq = tid & 7, jq = tid >> 3;   // jq 0..15
  int j0 = jt * 32;
  int ebase = et * 512;
  float acc[2][2] = {{0.f, 0.f}, {0.f, 0.f}};
  float sx[2] = {0.f, 0.f}, sq[2] = {0.f, 0.f};

  for (int ec = 0; ec < 8; ec++) {
    int eb = ebase + ec * 64;
    __syncthreads();
#pragma unroll
    for (int it = 0; it < 4; it++) {
      int f = it * 128 + tid;
      int row = f >> 4, e4 = f & 15;
      *(float4*)&xs[row][e4 * 4] =
          *(const float4*)(rpe + ((size_t)(rr * 128 + j0 + row)) * 1024 + eb + e4 * 4);
    }
#pragma unroll
    for (int it = 0; it < 2; it++) {
      int f = it * 128 + tid;
      int e = f >> 2, hh = f & 3;
      float4 u4 = *(const float4*)(ut_ws + ((size_t)rr * 1024 + eb + e) * 16 + hh * 4);
      float ge = lng[eb + e];
      us_t[hh * 4 + 0][e] = u4.x * ge;
      us_t[hh * 4 + 1][e] = u4.y * ge;
      us_t[hh * 4 + 2][e] = u4.z * ge;
      us_t[hh * 4 + 3][e] = u4.w * ge;
    }
    __syncthreads();
#pragma unroll
    for (int e4 = 0; e4 < 16; e4++) {
      float4 u0 = *(float4*)&us_t[hq * 2 + 0][e4 * 4];
      float4 u1 = *(float4*)&us_t[hq * 2 + 1][e4 * 4];
#pragma unroll
      for (int i = 0; i < 2; i++) {
        float4 xv = *(float4*)&xs[jq * 2 + i][e4 * 4];
        acc[i][0] += xv.x * u0.x + xv.y * u0.y + xv.z * u0.z + xv.w * u0.w;
        acc[i][1] += xv.x * u1.x + xv.y * u1.y + xv.z * u1.z + xv.w * u1.w;
      }
    }
#pragma unroll
    for (int t = 0; t < 2; t++) {
      int e4s = t * 8 + hq;
#pragma unroll
      for (int i = 0; i < 2; i++) {
        float4 xv = *(float4*)&xs[jq * 2 + i][e4s * 4];
        sx[i] += xv.x + xv.y + xv.z + xv.w;
        sq[i] += xv.x * xv.x + xv.y * xv.y + xv.z * xv.z + xv.w * xv.w;
      }
    }
  }
  float* sr = (et == 0) ? sraw0 : sraw1;
  float* sxp = (et == 0) ? sxp0 : sxp1;
  float* sqp = (et == 0) ? sqp0 : sqp1;
#pragma unroll
  for (int i = 0; i < 2; i++) {
    int j = j0 + jq * 2 + i;
    float2 o; o.x = acc[i][0]; o.y = acc[i][1];
    *(float2*)(sr + ((size_t)rr * 128 + j) * 16 + hq * 2) = o;
#pragma unroll
    for (int mk = 4; mk >= 1; mk >>= 1) {
      sx[i] += __shfl_xor(sx[i], mk, 8);
      sq[i] += __shfl_xor(sq[i], mk, 8);
    }
    if (hq == 0) {
      sxp[rr * 128 + j] = sx[i];
      sqp[rr * 128 + j] = sq[i];
    }
  }
}

// ---------------------------------------------------------------------------
// K5: combine partials + LN-affine + local softmax per (rr,h). grid 256, 256 thr.
__global__ __launch_bounds__(256) void k_attn_p(
    const float* __restrict__ sraw0, const float* __restrict__ sraw1,
    const float* __restrict__ sxp0, const float* __restrict__ sxp1,
    const float* __restrict__ sqp0, const float* __restrict__ sqp1,
    const float* __restrict__ Gu_ws, const float* __restrict__ S0_ws,
    float* __restrict__ s_ws,
    float* __restrict__ M_ws, float* __restrict__ Z_ws, float* __restrict__ C1_ws)
{
  int rr = blockIdx.x, tid = threadIdx.x;
  int h = tid >> 4, jl = tid & 15;
  float Gv = Gu_ws[rr * 16 + h];
  float S0v = S0_ws[rr * 16 + h];
  float sv[8], muv[8], rsvv[8];
  float m = -1e30f;
#pragma unroll
  for (int k = 0; k < 8; k++) {
    int j = jl + k * 16;
    size_t idx = ((size_t)rr * 128 + j) * 16 + h;
    float sxv = sxp0[rr * 128 + j] + sxp1[rr * 128 + j];
    float sqv = sqp0[rr * 128 + j] + sqp1[rr * 128 + j];
    float mu = sxv * (1.f / 1024.f);
    float rsv = rsqrtf(fmaxf(sqv * (1.f / 1024.f) - mu * mu, 0.f) + 1e-5f);
    float accv = sraw0[idx] + sraw1[idx];
    sv[k] = S0v + rsv * (accv - mu * Gv);
    muv[k] = mu; rsvv[k] = rsv;
    m = fmaxf(m, sv[k]);
  }
#pragma unroll
  for (int mk = 8; mk >= 1; mk >>= 1) m = fmaxf(m, __shfl_xor(m, mk, 16));
  float z = 0.f, c1 = 0.f;
#pragma unroll
  for (int k = 0; k < 8; k++) {
    int j = jl + k * 16;
    float p = expf(sv[k] - m);
    z += p;
    float p2 = p * rsvv[k];
    c1 += p2 * muv[k];
    s_ws[((size_t)rr * 128 + j) * 16 + h] = p2;
  }
#pragma unroll
  for (int mk = 8; mk >= 1; mk >>= 1) { z += __shfl_xor(z, mk, 16); c1 += __shfl_xor(c1, mk, 16); }
  if (jl == 0) {
    M_ws[rr * 16 + h] = m; Z_ws[rr * 16 + h] = z; C1_ws[rr * 16 + h] = c1;
  }
}

// ---------------------------------------------------------------------------
// K6: global softmax combine. grid 32 ((b,h)), 128 thr (one i each).
__global__ __launch_bounds__(128) void k_comb(
    const float* __restrict__ M_ws, const float* __restrict__ Z_ws, float* __restrict__ sc_ws)
{
  __shared__ float red[128];
  int b = blockIdx.x >> 4, h = blockIdx.x & 15;
  int i = threadIdx.x;
  int idx = ((b << 7) + i) * 16 + h;
  float ml = M_ws[idx];
  red[i] = ml;
  __syncthreads();
  for (int s = 64; s >= 1; s >>= 1) {
    if (i < s) red[i] = fmaxf(red[i], red[i + s]);
    __syncthreads();
  }
  float mg = red[0];
  __syncthreads();
  float zl = Z_ws[idx] * expf(ml - mg);
  red[i] = zl;
  __syncthreads();
  for (int s = 64; s >= 1; s >>= 1) {
    if (i < s) red[i] += red[i + s];
    __syncthreads();
  }
  float zg = red[0];
  sc_ws[idx] = expf(ml - mg) / zg;
}

// ---------------------------------------------------------------------------
// K7: PARTIAL PV: wp[jh][rr][e][h] = sum_{j in 64-half} p2[j,h]*x[j,e].
// grid (4 es, 2 jh, 256 rr) = 2048 blocks, 256 thr. Thread = 1 e-col, acc[16].
// 20 KB LDS -> 8 blocks/CU. Raw partials (no affine); k_qv combines+affines.
__global__ __launch_bounds__(256) void k_wun(
    const float* __restrict__ rpe, const float* __restrict__ p2_ws,
    float* __restrict__ w0_ws, float* __restrict__ w1_ws)
{
  __shared__ float xs[16][256];   // 16 KB
  __shared__ float p2s[64][16];   // 4 KB
  int es = blockIdx.x, jh = blockIdx.y, rr = blockIdx.z, tid = threadIdx.x;
  int e0 = es * 256, jbase = jh * 64;
  {
    int jj = tid >> 2, hh = tid & 3;  // 256 float4s exactly
    *(float4*)&p2s[jj][hh * 4] =
        *(const float4*)(p2_ws + ((size_t)(rr * 128 + jbase + jj)) * 16 + hh * 4);
  }
  float acc[16];
#pragma unroll
  for (int h = 0; h < 16; h++) acc[h] = 0.f;

#define WUN_ROW(xval) \
  acc[0] += (xval) * p0.x;  acc[1] += (xval) * p0.y;  \
  acc[2] += (xval) * p0.z;  acc[3] += (xval) * p0.w;  \
  acc[4] += (xval) * p1.x;  acc[5] += (xval) * p1.y;  \
  acc[6] += (xval) * p1.z;  acc[7] += (xval) * p1.w;  \
  acc[8] += (xval) * p2v.x; acc[9] += (xval) * p2v.y; \
  acc[10] += (xval) * p2v.z; acc[11] += (xval) * p2v.w; \
  acc[12] += (xval) * p3.x; acc[13] += (xval) * p3.y; \
  acc[14] += (xval) * p3.z; acc[15] += (xval) * p3.w;

  for (int jc = 0; jc < 4; jc++) {
    __syncthreads();
#pragma unroll
    for (int it = 0; it < 4; it++) {
      int f = it * 256 + tid;     // 1024 float4s
      int row = f >> 6, e4 = f & 63;
      *(float4*)&xs[row][e4 * 4] =
          *(const float4*)(rpe + ((size_t)(rr * 128 + jbase + jc * 16 + row)) * 1024 + e0 + e4 * 4);
    }
    __syncthreads();
#pragma unroll
    for (int j = 0; j < 16; j++) {
      int jj = jc * 16 + j;
      float x = xs[j][tid];
      float4 p0 = *(float4*)&p2s[jj][0];
      float4 p1 = *(float4*)&p2s[jj][4];
      float4 p2v = *(float4*)&p2s[jj][8];
      float4 p3 = *(float4*)&p2s[jj][12];
      WUN_ROW(x)
    }
  }
#undef WUN_ROW

  float* wp = (jh == 0 ? w0_ws : w1_ws) + ((size_t)rr * 1024 + e0 + tid) * 16;
#pragma unroll
  for (int hh = 0; hh < 4; hh++) {
    float4 o;
    o.x = acc[hh * 4 + 0]; o.y = acc[hh * 4 + 1];
    o.z = acc[hh * 4 + 2]; o.w = acc[hh * 4 + 3];
    *(float4*)(wp + hh * 4) = o;
  }
}

// ---------------------------------------------------------------------------
// K8: qv[rr][(g*2+hh)*64+d] += sum_e w[rr][e][g*2+hh]*Wrv[e][g*64+d],
// where w = ge*(w0+w1-C1[h]) + be*Z[h] computed at staging.
// grid (8 g, 16 rrt, 8 es) = 1024 blocks, 256 thr. K=128, Wrv prefetched.
__global__ __launch_bounds__(256) void k_qv(
    const float* __restrict__ w0_ws, const float* __restrict__ w1_ws,
    const float* __restrict__ Wrv,
    const float* __restrict__ lng, const float* __restrict__ lnb,
    const float* __restrict__ C1_ws, const float* __restrict__ Z_ws,
    float* __restrict__ qv_ws)
{
  __shared__ float As[32][133];  // [m][e] 17 KB, 133 pad -> conflict-free
  int g = blockIdx.x, rrt = blockIdx.y, es = blockIdx.z, tid = threadIdx.x;
  int rr0 = rrt * 16, e0 = es * 128;
  for (int f = tid; f < 2048; f += 256) {
    int rl = f >> 7, e = f & 127;
    size_t base = ((size_t)(rr0 + rl) * 1024 + e0 + e) * 16 + g * 2;
    float2 a = *(const float2*)(w0_ws + base);
    float2 b = *(const float2*)(w1_ws + base);
    float ge = lng[e0 + e], be = lnb[e0 + e];
    int ri = (rr0 + rl) * 16 + g * 2;
    float c0 = C1_ws[ri],     z0 = Z_ws[ri];
    float c1 = C1_ws[ri + 1], z1 = Z_ws[ri + 1];
    As[rl * 2 + 0][e] = ge * (a.x + b.x - c0) + be * z0;
    As[rl * 2 + 1][e] = ge * (a.y + b.y - c1) + be * z1;
  }
  __syncthreads();
  int cl = tid & 15, ms = tid >> 4;   // cols cl*4..+3, rows m=ms*2, ms*2+1
  const float* wp = Wrv + (size_t)e0 * 512 + g * 64 + cl * 4;
  float acc[2][4];
#pragma unroll
  for (int hh = 0; hh < 2; hh++)
#pragma unroll
    for (int s = 0; s < 4; s++) acc[hh][s] = 0.f;
  float4 wc = *(const float4*)wp;
  for (int e = 0; e < 128; e++) {
    int en = e + 1 < 128 ? e + 1 : 127;
    float4 wn = *(const float4*)(wp + (size_t)en * 512);
    float a0 = As[ms * 2][e], a1 = As[ms * 2 + 1][e];
    acc[0][0] += a0 * wc.x; acc[0][1] += a0 * wc.y; acc[0][2] += a0 * wc.z; acc[0][3] += a0 * wc.w;
    acc[1][0] += a1 * wc.x; acc[1][1] += a1 * wc.y; acc[1][2] += a1 * wc.z; acc[1][3] += a1 * wc.w;
    wc = wn;
  }
  int rr = rr0 + ms;
#pragma unroll
  for (int hh = 0; hh < 2; hh++) {
    float* qp = qv_ws + (size_t)rr * 1024 + (g * 2 + hh) * 64 + cl * 4;
#pragma unroll
    for (int s = 0; s < 4; s++) atomicAdd(qp + s, acc[hh][s]);
  }
}

// ---------------------------------------------------------------------------
// K9: out += qveff @ Wo, qveff[r][e] = sc[r,h]*(Z[r,h]*(v[r,gd]+brv[gd]) + qv_ws[r][e])
// grid (4 ct, 32 rt, 8 es) = 1024 blocks, 256 thr. 8 rows, K=128, Wo prefetched.
__global__ __launch_bounds__(256) void k_out(
    const float* __restrict__ qv_ws, const float* __restrict__ v_ws,
    const float* __restrict__ brv, const float* __restrict__ Z_ws,
    const float* __restrict__ sc_ws, const float* __restrict__ Wo,
    float* __restrict__ out)
{
  __shared__ float xs[8][128];  // 4 KB
  int ct = blockIdx.x, rt = blockIdx.y, es = blockIdx.z, tid = threadIdx.x;
  int row0 = rt * 8, e0 = es * 128, c0 = ct * 256;
  for (int f = tid; f < 1024; f += 256) {
    int r = f >> 7, ei = f & 127;
    int e = e0 + ei, row = row0 + r;
    int h = e >> 6, gg = h >> 1, dl = e & 63;
    float vb = v_ws[row * 512 + gg * 64 + dl] + brv[gg * 64 + dl];
    xs[r][ei] = sc_ws[row * 16 + h] * (Z_ws[row * 16 + h] * vb + qv_ws[(size_t)row * 1024 + e]);
  }
  __syncthreads();
  int cg = tid & 63, rs = tid >> 6;
  int c = c0 + cg * 4;
  const float* wp = Wo + (size_t)e0 * 1024 + c;
  float a0[4] = {0, 0, 0, 0}, a1[4] = {0, 0, 0, 0};
  float4 wc = *(const float4*)wp;
  for (int e = 0; e < 128; e++) {
    int en = e + 1 < 128 ? e + 1 : 127;
    float4 wn = *(const float4*)(wp + (size_t)en * 1024);
    float x0 = xs[rs][e], x1 = xs[rs + 4][e];
    a0[0] += x0 * wc.x; a0[1] += x0 * wc.y; a0[2] += x0 * wc.z; a0[3] += x0 * wc.w;
    a1[0] += x1 * wc.x; a1[1] += x1 * wc.y; a1[2] += x1 * wc.z; a1[3] += x1 * wc.w;
    wc = wn;
  }
#pragma unroll
  for (int s = 0; s < 4; s++) {
    atomicAdd(out + (size_t)(row0 + rs) * 1024 + c + s, a0[s]);
    atomicAdd(out + (size_t)(row0 + rs + 4) * 1024 + c + s, a1[s]);
  }
}

// ---------------------------------------------------------------------------
extern "C" void kernel_launch(void* const* d_in, const int* in_sizes, int n_in,
                              void* d_out, int out_size, void* d_ws, size_t ws_size,
                              hipStream_t stream) {
  (void)in_sizes; (void)n_in; (void)out_size; (void)ws_size;
  const float* Q   = (const float*)d_in[0];
  const float* K   = (const float*)d_in[1];
  const float* V   = (const float*)d_in[2];
  const float* rpe = (const float*)d_in[3];
  const float* lng = (const float*)d_in[4];
  const float* lnb = (const float*)d_in[5];
  const float* Wq  = (const float*)d_in[6];
  const float* bq  = (const float*)d_in[7];
  const float* Wk  = (const float*)d_in[8];
  const float* bk  = (const float*)d_in[9];
  const float* Wv  = (const float*)d_in[10];
  const float* bv  = (const float*)d_in[11];
  const float* Wrk = (const float*)d_in[12];
  const float* brk = (const float*)d_in[13];
  const float* Wrv = (const float*)d_in[14];
  const float* brv = (const float*)d_in[15];
  const float* Wo  = (const float*)d_in[16];
  const float* bo  = (const float*)d_in[17];
  float* out = (float*)d_out;

  float* ws    = (float*)d_ws;
  float* q_ws  = ws;                    // 262144
  float* k_ws  = q_ws + 262144;         // 131072
  float* v_ws  = k_ws + 131072;         // 131072
  float* ut_ws = v_ws + 131072;         // 4194304  (reused as w0_ws after k_dotp)
  float* S0_ws = ut_ws + 4194304;       // 4096
  float* Gu_ws = S0_ws + 4096;          // 4096
  float* s_ws  = Gu_ws + 4096;          // 524288   (p2)
  float* mu_ws = s_ws + 524288;         // 32768 (unused, layout keep)
  float* rs_ws = mu_ws + 32768;         // 32768 (unused)
  float* M_ws  = rs_ws + 32768;         // 4096
  float* Z_ws  = M_ws + 4096;           // 4096
  float* C1_ws = Z_ws + 4096;           // 4096
  float* sc_ws = C1_ws + 4096;          // 4096
  float* qv_ws = sc_ws + 4096;          // 262144
  float* sraw0 = qv_ws + 262144;        // 524288
  float* sraw1 = sraw0 + 524288;        // 524288
  float* sxp0  = sraw1 + 524288;        // 32768
  float* sxp1  = sxp0 + 32768;          // 32768
  float* sqp0  = sxp1 + 32768;          // 32768
  float* sqp1  = sqp0 + 32768;          // 32768
  float* w1_ws = sqp1 + 32768;          // 4194304  (~45 MB total)
  float* w0_ws = ut_ws;                 // reuse

  k_zero<<<dim3(256, 4), 256, 0, stream>>>(bq, bk, bv, bo, q_ws, k_ws, v_ws, qv_ws, out, Gu_ws);
  k_qkv<<<dim3(8, 32, 4), 256, 0, stream>>>(Q, K, V, Wq, Wk, Wv, q_ws, k_ws, v_ws);
  k_base<<<32, 128, 0, stream>>>(q_ws, k_ws, brk, S0_ws);
  k_uproj<<<dim3(8, 16, 8), 256, 0, stream>>>(q_ws, Wrk, lng, lnb, ut_ws, Gu_ws, S0_ws);
  k_dotp<<<dim3(4, 256, 2), 128, 0, stream>>>(rpe, lng, ut_ws,
                                              sraw0, sraw1, sxp0, sxp1, sqp0, sqp1);
  k_attn_p<<<256, 256, 0, stream>>>(sraw0, sraw1, sxp0, sxp1, sqp0, sqp1,
                                    Gu_ws, S0_ws, s_ws, M_ws, Z_ws, C1_ws);
  k_comb<<<32, 128, 0, stream>>>(M_ws, Z_ws, sc_ws);
  k_wun<<<dim3(4, 2, 256), 256, 0, stream>>>(rpe, s_ws, w0_ws, w1_ws);
  k_qv<<<dim3(8, 16, 8), 256, 0, stream>>>(w0_ws, w1_ws, Wrv, lng, lnb, C1_ws, Z_ws, qv_ws);
  k_out<<<dim3(4, 32, 8), 256, 0, stream>>>(qv_ws, v_ws, brv, Z_ws, sc_ws, Wo, out);
}

// Round 9
// 472.807 us; speedup vs baseline: 1.0245x; 1.0245x over previous
//
#include <hip/hip_runtime.h>

// B=2, L=128, E=1024, H=16, G=8, D=64, R=2. rows rr = b*128+i in [0,256).
// All inputs/outputs float32.
// R8: LDS-staged coalesced loads (scattered direct reads capped DRAM ~1 TB/s).
// R9/R11 lessons: stats slice-deduped; >=8 independent blocks/CU for overlap;
//   never below 1024 blocks.
// R12 (WIN, 506->470.7): k_dotp e-split partials, 2048 blocks, 13 KB LDS.
// R13 (FAIL, +14): k_wun j-split partials -> 33 MB w0/w1 round-trip cost more
//   than occupancy gained. Rule: split-reduce only with SMALL partials.
// R14: k_wun es-split instead: grid (8 es, 256 rr) = 2048 blocks, 128 thr,
//   16.3 KB LDS -> 8 blk/CU, NO extra global traffic, affine stays inline.
//   Everything else R12-exact (clean A/B vs 470.7).

// ---------------------------------------------------------------------------
// K0: seed biases / zeros. grid 256, 256 thr.
__global__ __launch_bounds__(256) void k_zero(
    const float* __restrict__ bq, const float* __restrict__ bk, const float* __restrict__ bv,
    const float* __restrict__ bo,
    float* __restrict__ q_ws, float* __restrict__ k_ws, float* __restrict__ v_ws,
    float* __restrict__ qv_ws, float* __restrict__ out, float* __restrict__ Gu_ws)
{
  int rr = blockIdx.x, tid = threadIdx.x;
#pragma unroll
  for (int s = 0; s < 4; s++) {
    int i = tid + s * 256;
    q_ws[rr * 1024 + i] = bq[i];
    qv_ws[rr * 1024 + i] = 0.f;
    out[rr * 1024 + i] = bo[i];
  }
#pragma unroll
  for (int s = 0; s < 2; s++) {
    int i = tid + s * 256;
    k_ws[rr * 512 + i] = bk[i];
    v_ws[rr * 512 + i] = bv[i];
  }
  int t = rr * 256 + tid;
  if (t < 4096) Gu_ws[t] = 0.f;
}

// ---------------------------------------------------------------------------
// K1: q/k/v projections. grid (8 ct, 32 rt, 4 es) = 1024 blocks, 256 thr.
__global__ __launch_bounds__(256) void k_qkv(
    const float* __restrict__ Q, const float* __restrict__ K, const float* __restrict__ V,
    const float* __restrict__ Wq, const float* __restrict__ Wk, const float* __restrict__ Wv,
    float* __restrict__ q_ws, float* __restrict__ k_ws, float* __restrict__ v_ws)
{
  __shared__ float xs[8][256];  // 8 KB
  int ct = blockIdx.x, rt = blockIdx.y, es = blockIdx.z, tid = threadIdx.x;
  const float* X; const float* W; float* out; int ldW, ldO, c0;
  if (ct < 4)      { X = Q; W = Wq; out = q_ws; ldW = 1024; ldO = 1024; c0 = ct * 256; }
  else if (ct < 6) { X = K; W = Wk; out = k_ws; ldW = 512;  ldO = 512;  c0 = (ct - 4) * 256; }
  else             { X = V; W = Wv; out = v_ws; ldW = 512;  ldO = 512;  c0 = (ct - 6) * 256; }
  int row0 = rt * 8, e0 = es * 256;
  for (int f = tid; f < 512; f += 256) {
    int r = f >> 6, e4 = f & 63;
    *(float4*)&xs[r][e4 * 4] = *(const float4*)(X + (size_t)(row0 + r) * 1024 + e0 + e4 * 4);
  }
  __syncthreads();
  int cg = tid & 63, rs = tid >> 6;
  int c = c0 + cg * 4;
  const float* wp = W + (size_t)e0 * ldW + c;
  float a0[4] = {0, 0, 0, 0}, a1[4] = {0, 0, 0, 0};
  float4 wc = *(const float4*)wp;
  for (int e = 0; e < 256; e++) {
    int en = e + 1 < 256 ? e + 1 : 255;
    float4 wn = *(const float4*)(wp + (size_t)en * ldW);
    float x0 = xs[rs][e], x1 = xs[rs + 4][e];
    a0[0] += x0 * wc.x; a0[1] += x0 * wc.y; a0[2] += x0 * wc.z; a0[3] += x0 * wc.w;
    a1[0] += x1 * wc.x; a1[1] += x1 * wc.y; a1[2] += x1 * wc.z; a1[3] += x1 * wc.w;
    wc = wn;
  }
#pragma unroll
  for (int s = 0; s < 4; s++) {
    atomicAdd(out + (size_t)(row0 + rs) * ldO + c + s, a0[s]);
    atomicAdd(out + (size_t)(row0 + rs + 4) * ldO + c + s, a1[s]);
  }
}

// ---------------------------------------------------------------------------
// K2: S0[r,h] = (q[r,h,:].(k[r,g,:]+brk[g,:])) / 8  (Bu added by k_uproj)
__global__ __launch_bounds__(256) void k_base(
    const float* __restrict__ q_ws, const float* __restrict__ k_ws,
    const float* __restrict__ brk, float* __restrict__ S0_ws)
{
  int t = blockIdx.x * 256 + threadIdx.x;  // 4096
  int r = t >> 4, h = t & 15, g = h >> 1;
  const float* qp = q_ws + r * 1024 + h * 64;
  const float* kp = k_ws + r * 512 + g * 64;
  const float* bp = brk + g * 64;
  float s = 0.f;
#pragma unroll
  for (int d4 = 0; d4 < 16; d4++) {
    float4 q4 = *(const float4*)(qp + d4 * 4);
    float4 k4 = *(const float4*)(kp + d4 * 4);
    float4 b4 = *(const float4*)(bp + d4 * 4);
    s += q4.x * (k4.x + b4.x) + q4.y * (k4.y + b4.y)
       + q4.z * (k4.z + b4.z) + q4.w * (k4.w + b4.w);
  }
  S0_ws[t] = s * 0.125f;
}

// ---------------------------------------------------------------------------
// K3: ut[rr][e][h] = 0.125 * sum_d q[rr,h*64+d] * Wrk[e, g*64+d], g=h>>1.
// grid (8 et, 16 rrt, 8 g) = 1024 blocks, 256 thr.
__global__ __launch_bounds__(256) void k_uproj(
    const float* __restrict__ q_ws, const float* __restrict__ Wrk,
    const float* __restrict__ lng, const float* __restrict__ lnb,
    float* __restrict__ ut_ws, float* __restrict__ Gu_ws, float* __restrict__ S0_ws)
{
  __shared__ float wt[64][128];  // [d][e_l] 32 KB
  __shared__ float qs[32][64];   // [m][d]   8 KB
  int et = blockIdx.x, rrt = blockIdx.y, g = blockIdx.z, tid = threadIdx.x;
  int e0 = et * 128, rr0 = rrt * 16;
  for (int f = tid; f < 2048; f += 256) {
    int er = f >> 4, dq = f & 15;
    float4 p = *(const float4*)(Wrk + (size_t)(e0 + er) * 512 + g * 64 + dq * 4);
    wt[dq * 4 + 0][er] = p.x; wt[dq * 4 + 1][er] = p.y;
    wt[dq * 4 + 2][er] = p.z; wt[dq * 4 + 3][er] = p.w;
  }
  for (int f = tid; f < 512; f += 256) {
    int m = f >> 4, dq = f & 15;
    int rr = rr0 + (m >> 1), h = g * 2 + (m & 1);
    float4 p = *(const float4*)(q_ws + (size_t)rr * 1024 + h * 64 + dq * 4);
    qs[m][dq * 4 + 0] = p.x; qs[m][dq * 4 + 1] = p.y;
    qs[m][dq * 4 + 2] = p.z; qs[m][dq * 4 + 3] = p.w;
  }
  __syncthreads();
  int eg = tid & 31, rs = tid >> 5;   // thread: 4 m (rs*4+i) x 4 e (eg*4+s)
  float acc[4][4];
#pragma unroll
  for (int i = 0; i < 4; i++)
#pragma unroll
    for (int s = 0; s < 4; s++) acc[i][s] = 0.f;
  for (int d = 0; d < 64; d++) {
    float4 wv = *(float4*)&wt[d][eg * 4];
#pragma unroll
    for (int i = 0; i < 4; i++) {
      float qv = qs[rs * 4 + i][d];
      acc[i][0] += qv * wv.x; acc[i][1] += qv * wv.y;
      acc[i][2] += qv * wv.z; acc[i][3] += qv * wv.w;
    }
  }
#pragma unroll
  for (int k = 0; k < 2; k++) {
    int rr = rr0 + rs * 2 + k;
#pragma unroll
    for (int s = 0; s < 4; s++) {
      int e = e0 + eg * 4 + s;
      float2 st;
      st.x = acc[2 * k][s] * 0.125f;
      st.y = acc[2 * k + 1][s] * 0.125f;
      *(float2*)(ut_ws + ((size_t)rr * 1024 + e) * 16 + g * 2) = st;
    }
  }
  float4 ge4 = *(const float4*)(lng + e0 + eg * 4);
  float4 be4 = *(const float4*)(lnb + e0 + eg * 4);
#pragma unroll
  for (int i = 0; i < 4; i++) {
    float pg = 0.125f * (ge4.x * acc[i][0] + ge4.y * acc[i][1] + ge4.z * acc[i][2] + ge4.w * acc[i][3]);
    float pb = 0.125f * (be4.x * acc[i][0] + be4.y * acc[i][1] + be4.z * acc[i][2] + be4.w * acc[i][3]);
#pragma unroll
    for (int mk = 16; mk >= 1; mk >>= 1) { pg += __shfl_xor(pg, mk); pb += __shfl_xor(pb, mk); }
    if (eg == 0) {
      int m = rs * 4 + i;
      int rr = rr0 + (m >> 1), h = g * 2 + (m & 1);
      atomicAdd(Gu_ws + rr * 16 + h, pg);
      atomicAdd(S0_ws + rr * 16 + h, pb);
    }
  }
}

// ---------------------------------------------------------------------------
// K4: PARTIAL scores. grid (4 jt, 256 rr, 2 et) = 2048 blocks, 128 thr.
// (unchanged from R12 — the win)
__global__ __launch_bounds__(128) void k_dotp(
    const float* __restrict__ rpe, const float* __restrict__ lng,
    const float* __restrict__ ut_ws,
    float* __restrict__ sraw0, float* __restrict__ sraw1,
    float* __restrict__ sxp0, float* __restrict__ sxp1,
    float* __restrict__ sqp0, float* __restrict__ sqp1)
{
  __shared__ float xs[32][68];    // 8.5 KB
  __shared__ float us_t[16][68];  // 4.25 KB
  int jt = blockIdx.x, rr = blockIdx.y, et = blockIdx.z, tid = threadIdx.x;
  int hq = tid & 7, jq = tid >> 3;   // jq 0..15
  int j0 = jt * 32;
  int ebase = et * 512;
  float acc[2][2] = {{0.f, 0.f}, {0.f, 0.f}};
  float sx[2] = {0.f, 0.f}, sq[2] = {0.f, 0.f};

  for (int ec = 0; ec < 8; ec++) {
    int eb = ebase + ec * 64;
    __syncthreads();
#pragma unroll
    for (int it = 0; it < 4; it++) {
      int f = it * 128 + tid;
      int row = f >> 4, e4 = f & 15;
      *(float4*)&xs[row][e4 * 4] =
          *(const float4*)(rpe + ((size_t)(rr * 128 + j0 + row)) * 1024 + eb + e4 * 4);
    }
#pragma unroll
    for (int it = 0; it < 2; it++) {
      int f = it * 128 + tid;
      int e = f >> 2, hh = f & 3;
      float4 u4 = *(const float4*)(ut_ws + ((size_t)rr * 1024 + eb + e) * 16 + hh * 4);
      float ge = lng[eb + e];
      us_t[hh * 4 + 0][e] = u4.x * ge;
      us_t[hh * 4 + 1][e] = u4.y * ge;
      us_t[hh * 4 + 2][e] = u4.z * ge;
      us_t[hh * 4 + 3][e] = u4.w * ge;
    }
    __syncthreads();
#pragma unroll
    for (int e4 = 0; e4 < 16; e4++) {
      float4 u0 = *(float4*)&us_t[hq * 2 + 0][e4 * 4];
      float4 u1 = *(float4*)&us_t[hq * 2 + 1][e4 * 4];
#pragma unroll
      for (int i = 0; i < 2; i++) {
        float4 xv = *(float4*)&xs[jq * 2 + i][e4 * 4];
        acc[i][0] += xv.x * u0.x + xv.y * u0.y + xv.z * u0.z + xv.w * u0.w;
        acc[i][1] += xv.x * u1.x + xv.y * u1.y + xv.z * u1.z + xv.w * u1.w;
      }
    }
#pragma unroll
    for (int t = 0; t < 2; t++) {
      int e4s = t * 8 + hq;
#pragma unroll
      for (int i = 0; i < 2; i++) {
        float4 xv = *(float4*)&xs[jq * 2 + i][e4s * 4];
        sx[i] += xv.x + xv.y + xv.z + xv.w;
        sq[i] += xv.x * xv.x + xv.y * xv.y + xv.z * xv.z + xv.w * xv.w;
      }
    }
  }
  float* sr = (et == 0) ? sraw0 : sraw1;
  float* sxp = (et == 0) ? sxp0 : sxp1;
  float* sqp = (et == 0) ? sqp0 : sqp1;
#pragma unroll
  for (int i = 0; i < 2; i++) {
    int j = j0 + jq * 2 + i;
    float2 o; o.x = acc[i][0]; o.y = acc[i][1];
    *(float2*)(sr + ((size_t)rr * 128 + j) * 16 + hq * 2) = o;
#pragma unroll
    for (int mk = 4; mk >= 1; mk >>= 1) {
      sx[i] += __shfl_xor(sx[i], mk, 8);
      sq[i] += __shfl_xor(sq[i], mk, 8);
    }
    if (hq == 0) {
      sxp[rr * 128 + j] = sx[i];
      sqp[rr * 128 + j] = sq[i];
    }
  }
}

// ---------------------------------------------------------------------------
// K5: combine partials + LN-affine + local softmax per (rr,h). grid 256, 256 thr.
__global__ __launch_bounds__(256) void k_attn_p(
    const float* __restrict__ sraw0, const float* __restrict__ sraw1,
    const float* __restrict__ sxp0, const float* __restrict__ sxp1,
    const float* __restrict__ sqp0, const float* __restrict__ sqp1,
    const float* __restrict__ Gu_ws, const float* __restrict__ S0_ws,
    float* __restrict__ s_ws,
    float* __restrict__ M_ws, float* __restrict__ Z_ws, float* __restrict__ C1_ws)
{
  int rr = blockIdx.x, tid = threadIdx.x;
  int h = tid >> 4, jl = tid & 15;
  float Gv = Gu_ws[rr * 16 + h];
  float S0v = S0_ws[rr * 16 + h];
  float sv[8], muv[8], rsvv[8];
  float m = -1e30f;
#pragma unroll
  for (int k = 0; k < 8; k++) {
    int j = jl + k * 16;
    size_t idx = ((size_t)rr * 128 + j) * 16 + h;
    float sxv = sxp0[rr * 128 + j] + sxp1[rr * 128 + j];
    float sqv = sqp0[rr * 128 + j] + sqp1[rr * 128 + j];
    float mu = sxv * (1.f / 1024.f);
    float rsv = rsqrtf(fmaxf(sqv * (1.f / 1024.f) - mu * mu, 0.f) + 1e-5f);
    float accv = sraw0[idx] + sraw1[idx];
    sv[k] = S0v + rsv * (accv - mu * Gv);
    muv[k] = mu; rsvv[k] = rsv;
    m = fmaxf(m, sv[k]);
  }
#pragma unroll
  for (int mk = 8; mk >= 1; mk >>= 1) m = fmaxf(m, __shfl_xor(m, mk, 16));
  float z = 0.f, c1 = 0.f;
#pragma unroll
  for (int k = 0; k < 8; k++) {
    int j = jl + k * 16;
    float p = expf(sv[k] - m);
    z += p;
    float p2 = p * rsvv[k];
    c1 += p2 * muv[k];
    s_ws[((size_t)rr * 128 + j) * 16 + h] = p2;
  }
#pragma unroll
  for (int mk = 8; mk >= 1; mk >>= 1) { z += __shfl_xor(z, mk, 16); c1 += __shfl_xor(c1, mk, 16); }
  if (jl == 0) {
    M_ws[rr * 16 + h] = m; Z_ws[rr * 16 + h] = z; C1_ws[rr * 16 + h] = c1;
  }
}

// ---------------------------------------------------------------------------
// K6: global softmax combine. grid 32 ((b,h)), 128 thr (one i each).
__global__ __launch_bounds__(128) void k_comb(
    const float* __restrict__ M_ws, const float* __restrict__ Z_ws, float* __restrict__ sc_ws)
{
  __shared__ float red[128];
  int b = blockIdx.x >> 4, h = blockIdx.x & 15;
  int i = threadIdx.x;
  int idx = ((b << 7) + i) * 16 + h;
  float ml = M_ws[idx];
  red[i] = ml;
  __syncthreads();
  for (int s = 64; s >= 1; s >>= 1) {
    if (i < s) red[i] = fmaxf(red[i], red[i + s]);
    __syncthreads();
  }
  float mg = red[0];
  __syncthreads();
  float zl = Z_ws[idx] * expf(ml - mg);
  red[i] = zl;
  __syncthreads();
  for (int s = 64; s >= 1; s >>= 1) {
    if (i < s) red[i] += red[i + s];
    __syncthreads();
  }
  float zg = red[0];
  sc_ws[idx] = expf(ml - mg) / zg;
}

// ---------------------------------------------------------------------------
// K7: w_t[rr][e][h] = g_e*(sum_j p2[j,h]*x[j,e] - C1[h]) + b_e*Z[h]
// R14: grid (8 es, 256 rr) = 2048 blocks, 128 thr. Thread = 1 e-col, acc[16].
// xs[16][128] 8 KB + p2s 8 KB = 16.3 KB -> 8 blk/CU (16 waves), independent
// phases overlap. No extra global traffic (vs R13's failed partial split).
__global__ __launch_bounds__(128) void k_wun(
    const float* __restrict__ rpe, const float* __restrict__ lng, const float* __restrict__ lnb,
    const float* __restrict__ p2_ws,
    const float* __restrict__ Z_ws, const float* __restrict__ C1_ws,
    float* __restrict__ w_ws)
{
  __shared__ float xs[16][128];   // 8 KB
  __shared__ float p2s[128][16];  // 8 KB
  __shared__ float C1S[16], ZS[16];
  int es = blockIdx.x, rr = blockIdx.y, tid = threadIdx.x;
  int e0 = es * 128;
#pragma unroll
  for (int it = 0; it < 4; it++) {
    int f = it * 128 + tid;       // 512 float4s of p2
    int jj = f >> 2, hh = f & 3;
    *(float4*)&p2s[jj][hh * 4] = *(const float4*)(p2_ws + ((size_t)rr * 128 + jj) * 16 + hh * 4);
  }
  if (tid < 16) { C1S[tid] = C1_ws[rr * 16 + tid]; ZS[tid] = Z_ws[rr * 16 + tid]; }
  float acc[16];
#pragma unroll
  for (int h = 0; h < 16; h++) acc[h] = 0.f;

#define WUN_ROW(xval) \
  acc[0] += (xval) * p0.x;  acc[1] += (xval) * p0.y;  \
  acc[2] += (xval) * p0.z;  acc[3] += (xval) * p0.w;  \
  acc[4] += (xval) * p1.x;  acc[5] += (xval) * p1.y;  \
  acc[6] += (xval) * p1.z;  acc[7] += (xval) * p1.w;  \
  acc[8] += (xval) * p2v.x; acc[9] += (xval) * p2v.y; \
  acc[10] += (xval) * p2v.z; acc[11] += (xval) * p2v.w; \
  acc[12] += (xval) * p3.x; acc[13] += (xval) * p3.y; \
  acc[14] += (xval) * p3.z; acc[15] += (xval) * p3.w;

  for (int jc = 0; jc < 8; jc++) {
    __syncthreads();
#pragma unroll
    for (int it = 0; it < 4; it++) {
      int f = it * 128 + tid;     // 512 float4s: 16 rows x 128 e
      int row = f >> 5, e4 = f & 31;
      *(float4*)&xs[row][e4 * 4] =
          *(const float4*)(rpe + ((size_t)(rr * 128 + jc * 16 + row)) * 1024 + e0 + e4 * 4);
    }
    __syncthreads();
#pragma unroll
    for (int j = 0; j < 16; j++) {
      int jj = jc * 16 + j;
      float x = xs[j][tid];
      float4 p0 = *(float4*)&p2s[jj][0];
      float4 p1 = *(float4*)&p2s[jj][4];
      float4 p2v = *(float4*)&p2s[jj][8];
      float4 p3 = *(float4*)&p2s[jj][12];
      WUN_ROW(x)
    }
  }
#undef WUN_ROW

  int e = e0 + tid;
  float ge = lng[e], be = lnb[e];
  float* wp = w_ws + ((size_t)rr * 1024 + e) * 16;
#pragma unroll
  for (int hh = 0; hh < 4; hh++) {
    float4 o;
    o.x = ge * (acc[hh * 4 + 0] - C1S[hh * 4 + 0]) + be * ZS[hh * 4 + 0];
    o.y = ge * (acc[hh * 4 + 1] - C1S[hh * 4 + 1]) + be * ZS[hh * 4 + 1];
    o.z = ge * (acc[hh * 4 + 2] - C1S[hh * 4 + 2]) + be * ZS[hh * 4 + 2];
    o.w = ge * (acc[hh * 4 + 3] - C1S[hh * 4 + 3]) + be * ZS[hh * 4 + 3];
    *(float4*)(wp + hh * 4) = o;
  }
}

// ---------------------------------------------------------------------------
// K8: qv[rr][(g*2+hh)*64+d] += sum_e w_t[rr][e][g*2+hh]*Wrv[e][g*64+d]
// grid (8 g, 16 rrt, 8 es) = 1024 blocks, 256 thr. K=128, Wrv prefetched.
__global__ __launch_bounds__(256) void k_qv(
    const float* __restrict__ w_ws, const float* __restrict__ Wrv,
    float* __restrict__ qv_ws)
{
  __shared__ float As[32][133];  // [m][e] 17 KB, 133 pad -> conflict-free
  int g = blockIdx.x, rrt = blockIdx.y, es = blockIdx.z, tid = threadIdx.x;
  int rr0 = rrt * 16, e0 = es * 128;
  for (int f = tid; f < 2048; f += 256) {
    int rl = f >> 7, e = f & 127;
    float2 w2 = *(const float2*)(w_ws + ((size_t)(rr0 + rl) * 1024 + e0 + e) * 16 + g * 2);
    As[rl * 2 + 0][e] = w2.x;
    As[rl * 2 + 1][e] = w2.y;
  }
  __syncthreads();
  int cl = tid & 15, ms = tid >> 4;   // cols cl*4..+3, rows m=ms*2, ms*2+1
  const float* wp = Wrv + (size_t)e0 * 512 + g * 64 + cl * 4;
  float acc[2][4];
#pragma unroll
  for (int hh = 0; hh < 2; hh++)
#pragma unroll
    for (int s = 0; s < 4; s++) acc[hh][s] = 0.f;
  float4 wc = *(const float4*)wp;
  for (int e = 0; e < 128; e++) {
    int en = e + 1 < 128 ? e + 1 : 127;
    float4 wn = *(const float4*)(wp + (size_t)en * 512);
    float a0 = As[ms * 2][e], a1 = As[ms * 2 + 1][e];
    acc[0][0] += a0 * wc.x; acc[0][1] += a0 * wc.y; acc[0][2] += a0 * wc.z; acc[0][3] += a0 * wc.w;
    acc[1][0] += a1 * wc.x; acc[1][1] += a1 * wc.y; acc[1][2] += a1 * wc.z; acc[1][3] += a1 * wc.w;
    wc = wn;
  }
  int rr = rr0 + ms;
#pragma unroll
  for (int hh = 0; hh < 2; hh++) {
    float* qp = qv_ws + (size_t)rr * 1024 + (g * 2 + hh) * 64 + cl * 4;
#pragma unroll
    for (int s = 0; s < 4; s++) atomicAdd(qp + s, acc[hh][s]);
  }
}

// ---------------------------------------------------------------------------
// K9: out += qveff @ Wo, qveff[r][e] = sc[r,h]*(Z[r,h]*(v[r,gd]+brv[gd]) + qv_ws[r][e])
// grid (4 ct, 32 rt, 8 es) = 1024 blocks, 256 thr. 8 rows, K=128, Wo prefetched.
__global__ __launch_bounds__(256) void k_out(
    const float* __restrict__ qv_ws, const float* __restrict__ v_ws,
    const float* __restrict__ brv, const float* __restrict__ Z_ws,
    const float* __restrict__ sc_ws, const float* __restrict__ Wo,
    float* __restrict__ out)
{
  __shared__ float xs[8][128];  // 4 KB
  int ct = blockIdx.x, rt = blockIdx.y, es = blockIdx.z, tid = threadIdx.x;
  int row0 = rt * 8, e0 = es * 128, c0 = ct * 256;
  for (int f = tid; f < 1024; f += 256) {
    int r = f >> 7, ei = f & 127;
    int e = e0 + ei, row = row0 + r;
    int h = e >> 6, gg = h >> 1, dl = e & 63;
    float vb = v_ws[row * 512 + gg * 64 + dl] + brv[gg * 64 + dl];
    xs[r][ei] = sc_ws[row * 16 + h] * (Z_ws[row * 16 + h] * vb + qv_ws[(size_t)row * 1024 + e]);
  }
  __syncthreads();
  int cg = tid & 63, rs = tid >> 6;
  int c = c0 + cg * 4;
  const float* wp = Wo + (size_t)e0 * 1024 + c;
  float a0[4] = {0, 0, 0, 0}, a1[4] = {0, 0, 0, 0};
  float4 wc = *(const float4*)wp;
  for (int e = 0; e < 128; e++) {
    int en = e + 1 < 128 ? e + 1 : 127;
    float4 wn = *(const float4*)(wp + (size_t)en * 1024);
    float x0 = xs[rs][e], x1 = xs[rs + 4][e];
    a0[0] += x0 * wc.x; a0[1] += x0 * wc.y; a0[2] += x0 * wc.z; a0[3] += x0 * wc.w;
    a1[0] += x1 * wc.x; a1[1] += x1 * wc.y; a1[2] += x1 * wc.z; a1[3] += x1 * wc.w;
    wc = wn;
  }
#pragma unroll
  for (int s = 0; s < 4; s++) {
    atomicAdd(out + (size_t)(row0 + rs) * 1024 + c + s, a0[s]);
    atomicAdd(out + (size_t)(row0 + rs + 4) * 1024 + c + s, a1[s]);
  }
}

// ---------------------------------------------------------------------------
extern "C" void kernel_launch(void* const* d_in, const int* in_sizes, int n_in,
                              void* d_out, int out_size, void* d_ws, size_t ws_size,
                              hipStream_t stream) {
  (void)in_sizes; (void)n_in; (void)out_size; (void)ws_size;
  const float* Q   = (const float*)d_in[0];
  const float* K   = (const float*)d_in[1];
  const float* V   = (const float*)d_in[2];
  const float* rpe = (const float*)d_in[3];
  const float* lng = (const float*)d_in[4];
  const float* lnb = (const float*)d_in[5];
  const float* Wq  = (const float*)d_in[6];
  const float* bq  = (const float*)d_in[7];
  const float* Wk  = (const float*)d_in[8];
  const float* bk  = (const float*)d_in[9];
  const float* Wv  = (const float*)d_in[10];
  const float* bv  = (const float*)d_in[11];
  const float* Wrk = (const float*)d_in[12];
  const float* brk = (const float*)d_in[13];
  const float* Wrv = (const float*)d_in[14];
  const float* brv = (const float*)d_in[15];
  const float* Wo  = (const float*)d_in[16];
  const float* bo  = (const float*)d_in[17];
  float* out = (float*)d_out;

  float* ws    = (float*)d_ws;
  float* q_ws  = ws;                    // 262144
  float* k_ws  = q_ws + 262144;         // 131072
  float* v_ws  = k_ws + 131072;         // 131072
  float* ut_ws = v_ws + 131072;         // 4194304  (reused as w_ws after k_dotp)
  float* S0_ws = ut_ws + 4194304;       // 4096
  float* Gu_ws = S0_ws + 4096;          // 4096
  float* s_ws  = Gu_ws + 4096;          // 524288   (p2)
  float* mu_ws = s_ws + 524288;         // 32768 (unused, layout keep)
  float* rs_ws = mu_ws + 32768;         // 32768 (unused)
  float* M_ws  = rs_ws + 32768;         // 4096
  float* Z_ws  = M_ws + 4096;           // 4096
  float* C1_ws = Z_ws + 4096;           // 4096
  float* sc_ws = C1_ws + 4096;          // 4096
  float* qv_ws = sc_ws + 4096;          // 262144
  float* sraw0 = qv_ws + 262144;        // 524288
  float* sraw1 = sraw0 + 524288;        // 524288
  float* sxp0  = sraw1 + 524288;        // 32768
  float* sxp1  = sxp0 + 32768;          // 32768
  float* sqp0  = sxp1 + 32768;          // 32768
  float* sqp1  = sqp0 + 32768;          // 32768  (~28 MB total)
  float* w_ws  = ut_ws;                 // reuse

  k_zero<<<256, 256, 0, stream>>>(bq, bk, bv, bo, q_ws, k_ws, v_ws, qv_ws, out, Gu_ws);
  k_qkv<<<dim3(8, 32, 4), 256, 0, stream>>>(Q, K, V, Wq, Wk, Wv, q_ws, k_ws, v_ws);
  k_base<<<16, 256, 0, stream>>>(q_ws, k_ws, brk, S0_ws);
  k_uproj<<<dim3(8, 16, 8), 256, 0, stream>>>(q_ws, Wrk, lng, lnb, ut_ws, Gu_ws, S0_ws);
  k_dotp<<<dim3(4, 256, 2), 128, 0, stream>>>(rpe, lng, ut_ws,
                                              sraw0, sraw1, sxp0, sxp1, sqp0, sqp1);
  k_attn_p<<<256, 256, 0, stream>>>(sraw0, sraw1, sxp0, sxp1, sqp0, sqp1,
                                    Gu_ws, S0_ws, s_ws, M_ws, Z_ws, C1_ws);
  k_comb<<<32, 128, 0, stream>>>(M_ws, Z_ws, sc_ws);
  k_wun<<<dim3(8, 256), 128, 0, stream>>>(rpe, lng, lnb, s_ws, Z_ws, C1_ws, w_ws);
  k_qv<<<dim3(8, 16, 8), 256, 0, stream>>>(w_ws, Wrv, qv_ws);
  k_out<<<dim3(4, 32, 8), 256, 0, stream>>>(qv_ws, v_ws, brv, Z_ws, sc_ws, Wo, out);
}

// Round 10
// 470.613 us; speedup vs baseline: 1.0293x; 1.0047x over previous
//
#include <hip/hip_runtime.h>

// B=2, L=128, E=1024, H=16, G=8, D=64, R=2. rows rr = b*128+i in [0,256).
// All inputs/outputs float32.
// R8: LDS-staged coalesced loads (scattered direct reads cap DRAM ~1 TB/s).
// R9/R11: stats slice-deduped; >=8 independent blocks/CU; >=1024 blocks.
// R12 (WIN, 506->470.7): k_dotp e-split partials, 2048 blocks, 13 KB LDS.
// R13 (FAIL +14): k_wun j-split partials -> 33 MB round-trip. Small partials only.
// R14 (NEUTRAL): k_wun es-split 8 blk/CU == R12's 2 blk/CU -> k_wun not
//   stall-bound (rpe re-read is L3-served). Big residual is elsewhere.
// R15: cut serial stages: fold k_base into k_attn_p (inline 64-d base dot),
//   fold k_comb into k_out prologue (per-block mg/zg reduce, drop sc_ws).
//   10 -> 8 dispatches. All compute kernels R14-exact.

// ---------------------------------------------------------------------------
// K0: seed biases / zeros. grid 256, 256 thr.
__global__ __launch_bounds__(256) void k_zero(
    const float* __restrict__ bq, const float* __restrict__ bk, const float* __restrict__ bv,
    const float* __restrict__ bo,
    float* __restrict__ q_ws, float* __restrict__ k_ws, float* __restrict__ v_ws,
    float* __restrict__ qv_ws, float* __restrict__ out,
    float* __restrict__ Gu_ws, float* __restrict__ S0_ws)
{
  int rr = blockIdx.x, tid = threadIdx.x;
#pragma unroll
  for (int s = 0; s < 4; s++) {
    int i = tid + s * 256;
    q_ws[rr * 1024 + i] = bq[i];
    qv_ws[rr * 1024 + i] = 0.f;
    out[rr * 1024 + i] = bo[i];
  }
#pragma unroll
  for (int s = 0; s < 2; s++) {
    int i = tid + s * 256;
    k_ws[rr * 512 + i] = bk[i];
    v_ws[rr * 512 + i] = bv[i];
  }
  int t = rr * 256 + tid;
  if (t < 4096) { Gu_ws[t] = 0.f; S0_ws[t] = 0.f; }
}

// ---------------------------------------------------------------------------
// K1: q/k/v projections. grid (8 ct, 32 rt, 4 es) = 1024 blocks, 256 thr.
__global__ __launch_bounds__(256) void k_qkv(
    const float* __restrict__ Q, const float* __restrict__ K, const float* __restrict__ V,
    const float* __restrict__ Wq, const float* __restrict__ Wk, const float* __restrict__ Wv,
    float* __restrict__ q_ws, float* __restrict__ k_ws, float* __restrict__ v_ws)
{
  __shared__ float xs[8][256];  // 8 KB
  int ct = blockIdx.x, rt = blockIdx.y, es = blockIdx.z, tid = threadIdx.x;
  const float* X; const float* W; float* out; int ldW, ldO, c0;
  if (ct < 4)      { X = Q; W = Wq; out = q_ws; ldW = 1024; ldO = 1024; c0 = ct * 256; }
  else if (ct < 6) { X = K; W = Wk; out = k_ws; ldW = 512;  ldO = 512;  c0 = (ct - 4) * 256; }
  else             { X = V; W = Wv; out = v_ws; ldW = 512;  ldO = 512;  c0 = (ct - 6) * 256; }
  int row0 = rt * 8, e0 = es * 256;
  for (int f = tid; f < 512; f += 256) {
    int r = f >> 6, e4 = f & 63;
    *(float4*)&xs[r][e4 * 4] = *(const float4*)(X + (size_t)(row0 + r) * 1024 + e0 + e4 * 4);
  }
  __syncthreads();
  int cg = tid & 63, rs = tid >> 6;
  int c = c0 + cg * 4;
  const float* wp = W + (size_t)e0 * ldW + c;
  float a0[4] = {0, 0, 0, 0}, a1[4] = {0, 0, 0, 0};
  float4 wc = *(const float4*)wp;
  for (int e = 0; e < 256; e++) {
    int en = e + 1 < 256 ? e + 1 : 255;
    float4 wn = *(const float4*)(wp + (size_t)en * ldW);
    float x0 = xs[rs][e], x1 = xs[rs + 4][e];
    a0[0] += x0 * wc.x; a0[1] += x0 * wc.y; a0[2] += x0 * wc.z; a0[3] += x0 * wc.w;
    a1[0] += x1 * wc.x; a1[1] += x1 * wc.y; a1[2] += x1 * wc.z; a1[3] += x1 * wc.w;
    wc = wn;
  }
#pragma unroll
  for (int s = 0; s < 4; s++) {
    atomicAdd(out + (size_t)(row0 + rs) * ldO + c + s, a0[s]);
    atomicAdd(out + (size_t)(row0 + rs + 4) * ldO + c + s, a1[s]);
  }
}

// ---------------------------------------------------------------------------
// K3: ut[rr][e][h] = 0.125 * sum_d q[rr,h*64+d] * Wrk[e, g*64+d], g=h>>1.
// grid (8 et, 16 rrt, 8 g) = 1024 blocks, 256 thr.
__global__ __launch_bounds__(256) void k_uproj(
    const float* __restrict__ q_ws, const float* __restrict__ Wrk,
    const float* __restrict__ lng, const float* __restrict__ lnb,
    float* __restrict__ ut_ws, float* __restrict__ Gu_ws, float* __restrict__ S0_ws)
{
  __shared__ float wt[64][128];  // [d][e_l] 32 KB
  __shared__ float qs[32][64];   // [m][d]   8 KB
  int et = blockIdx.x, rrt = blockIdx.y, g = blockIdx.z, tid = threadIdx.x;
  int e0 = et * 128, rr0 = rrt * 16;
  for (int f = tid; f < 2048; f += 256) {
    int er = f >> 4, dq = f & 15;
    float4 p = *(const float4*)(Wrk + (size_t)(e0 + er) * 512 + g * 64 + dq * 4);
    wt[dq * 4 + 0][er] = p.x; wt[dq * 4 + 1][er] = p.y;
    wt[dq * 4 + 2][er] = p.z; wt[dq * 4 + 3][er] = p.w;
  }
  for (int f = tid; f < 512; f += 256) {
    int m = f >> 4, dq = f & 15;
    int rr = rr0 + (m >> 1), h = g * 2 + (m & 1);
    float4 p = *(const float4*)(q_ws + (size_t)rr * 1024 + h * 64 + dq * 4);
    qs[m][dq * 4 + 0] = p.x; qs[m][dq * 4 + 1] = p.y;
    qs[m][dq * 4 + 2] = p.z; qs[m][dq * 4 + 3] = p.w;
  }
  __syncthreads();
  int eg = tid & 31, rs = tid >> 5;   // thread: 4 m (rs*4+i) x 4 e (eg*4+s)
  float acc[4][4];
#pragma unroll
  for (int i = 0; i < 4; i++)
#pragma unroll
    for (int s = 0; s < 4; s++) acc[i][s] = 0.f;
  for (int d = 0; d < 64; d++) {
    float4 wv = *(float4*)&wt[d][eg * 4];
#pragma unroll
    for (int i = 0; i < 4; i++) {
      float qv = qs[rs * 4 + i][d];
      acc[i][0] += qv * wv.x; acc[i][1] += qv * wv.y;
      acc[i][2] += qv * wv.z; acc[i][3] += qv * wv.w;
    }
  }
#pragma unroll
  for (int k = 0; k < 2; k++) {
    int rr = rr0 + rs * 2 + k;
#pragma unroll
    for (int s = 0; s < 4; s++) {
      int e = e0 + eg * 4 + s;
      float2 st;
      st.x = acc[2 * k][s] * 0.125f;
      st.y = acc[2 * k + 1][s] * 0.125f;
      *(float2*)(ut_ws + ((size_t)rr * 1024 + e) * 16 + g * 2) = st;
    }
  }
  float4 ge4 = *(const float4*)(lng + e0 + eg * 4);
  float4 be4 = *(const float4*)(lnb + e0 + eg * 4);
#pragma unroll
  for (int i = 0; i < 4; i++) {
    float pg = 0.125f * (ge4.x * acc[i][0] + ge4.y * acc[i][1] + ge4.z * acc[i][2] + ge4.w * acc[i][3]);
    float pb = 0.125f * (be4.x * acc[i][0] + be4.y * acc[i][1] + be4.z * acc[i][2] + be4.w * acc[i][3]);
#pragma unroll
    for (int mk = 16; mk >= 1; mk >>= 1) { pg += __shfl_xor(pg, mk); pb += __shfl_xor(pb, mk); }
    if (eg == 0) {
      int m = rs * 4 + i;
      int rr = rr0 + (m >> 1), h = g * 2 + (m & 1);
      atomicAdd(Gu_ws + rr * 16 + h, pg);
      atomicAdd(S0_ws + rr * 16 + h, pb);
    }
  }
}

// ---------------------------------------------------------------------------
// K4: PARTIAL scores. grid (4 jt, 256 rr, 2 et) = 2048 blocks, 128 thr.
// (unchanged from R12 — the win)
__global__ __launch_bounds__(128) void k_dotp(
    const float* __restrict__ rpe, const float* __restrict__ lng,
    const float* __restrict__ ut_ws,
    float* __restrict__ sraw0, float* __restrict__ sraw1,
    float* __restrict__ sxp0, float* __restrict__ sxp1,
    float* __restrict__ sqp0, float* __restrict__ sqp1)
{
  __shared__ float xs[32][68];    // 8.5 KB
  __shared__ float us_t[16][68];  // 4.25 KB
  int jt = blockIdx.x, rr = blockIdx.y, et = blockIdx.z, tid = threadIdx.x;
  int hq = tid & 7, jq = tid >> 3;   // jq 0..15
  int j0 = jt * 32;
  int ebase = et * 512;
  float acc[2][2] = {{0.f, 0.f}, {0.f, 0.f}};
  float sx[2] = {0.f, 0.f}, sq[2] = {0.f, 0.f};

  for (int ec = 0; ec < 8; ec++) {
    int eb = ebase + ec * 64;
    __syncthreads();
#pragma unroll
    for (int it = 0; it < 4; it++) {
      int f = it * 128 + tid;
      int row = f >> 4, e4 = f & 15;
      *(float4*)&xs[row][e4 * 4] =
          *(const float4*)(rpe + ((size_t)(rr * 128 + j0 + row)) * 1024 + eb + e4 * 4);
    }
#pragma unroll
    for (int it = 0; it < 2; it++) {
      int f = it * 128 + tid;
      int e = f >> 2, hh = f & 3;
      float4 u4 = *(const float4*)(ut_ws + ((size_t)rr * 1024 + eb + e) * 16 + hh * 4);
      float ge = lng[eb + e];
      us_t[hh * 4 + 0][e] = u4.x * ge;
      us_t[hh * 4 + 1][e] = u4.y * ge;
      us_t[hh * 4 + 2][e] = u4.z * ge;
      us_t[hh * 4 + 3][e] = u4.w * ge;
    }
    __syncthreads();
#pragma unroll
    for (int e4 = 0; e4 < 16; e4++) {
      float4 u0 = *(float4*)&us_t[hq * 2 + 0][e4 * 4];
      float4 u1 = *(float4*)&us_t[hq * 2 + 1][e4 * 4];
#pragma unroll
      for (int i = 0; i < 2; i++) {
        float4 xv = *(float4*)&xs[jq * 2 + i][e4 * 4];
        acc[i][0] += xv.x * u0.x + xv.y * u0.y + xv.z * u0.z + xv.w * u0.w;
        acc[i][1] += xv.x * u1.x + xv.y * u1.y + xv.z * u1.z + xv.w * u1.w;
      }
    }
#pragma unroll
    for (int t = 0; t < 2; t++) {
      int e4s = t * 8 + hq;
#pragma unroll
      for (int i = 0; i < 2; i++) {
        float4 xv = *(float4*)&xs[jq * 2 + i][e4s * 4];
        sx[i] += xv.x + xv.y + xv.z + xv.w;
        sq[i] += xv.x * xv.x + xv.y * xv.y + xv.z * xv.z + xv.w * xv.w;
      }
    }
  }
  float* sr = (et == 0) ? sraw0 : sraw1;
  float* sxp = (et == 0) ? sxp0 : sxp1;
  float* sqp = (et == 0) ? sqp0 : sqp1;
#pragma unroll
  for (int i = 0; i < 2; i++) {
    int j = j0 + jq * 2 + i;
    float2 o; o.x = acc[i][0]; o.y = acc[i][1];
    *(float2*)(sr + ((size_t)rr * 128 + j) * 16 + hq * 2) = o;
#pragma unroll
    for (int mk = 4; mk >= 1; mk >>= 1) {
      sx[i] += __shfl_xor(sx[i], mk, 8);
      sq[i] += __shfl_xor(sq[i], mk, 8);
    }
    if (hq == 0) {
      sxp[rr * 128 + j] = sx[i];
      sqp[rr * 128 + j] = sq[i];
    }
  }
}

// ---------------------------------------------------------------------------
// K5: combine partials + inline base dot (was k_base) + LN-affine + local
// softmax per (rr,h). grid 256, 256 thr. Thread (h=tid>>4, jl=tid&15).
// Base dot: 16 jl lanes each cover d=jl*4..+3, shfl width-16 sum.
__global__ __launch_bounds__(256) void k_attn_p(
    const float* __restrict__ sraw0, const float* __restrict__ sraw1,
    const float* __restrict__ sxp0, const float* __restrict__ sxp1,
    const float* __restrict__ sqp0, const float* __restrict__ sqp1,
    const float* __restrict__ q_ws, const float* __restrict__ k_ws,
    const float* __restrict__ brk,
    const float* __restrict__ Gu_ws, const float* __restrict__ S0_ws,
    float* __restrict__ s_ws,
    float* __restrict__ M_ws, float* __restrict__ Z_ws, float* __restrict__ C1_ws)
{
  int rr = blockIdx.x, tid = threadIdx.x;
  int h = tid >> 4, jl = tid & 15;
  int g = h >> 1;
  // base dot (folded k_base): q[rr,h,:].(k[rr,g,:]+brk[g,:]) / 8
  float4 q4 = *(const float4*)(q_ws + (size_t)rr * 1024 + h * 64 + jl * 4);
  float4 k4 = *(const float4*)(k_ws + (size_t)rr * 512 + g * 64 + jl * 4);
  float4 b4 = *(const float4*)(brk + g * 64 + jl * 4);
  float pb = q4.x * (k4.x + b4.x) + q4.y * (k4.y + b4.y)
           + q4.z * (k4.z + b4.z) + q4.w * (k4.w + b4.w);
#pragma unroll
  for (int mk = 8; mk >= 1; mk >>= 1) pb += __shfl_xor(pb, mk, 16);
  float S0v = S0_ws[rr * 16 + h] + pb * 0.125f;
  float Gv = Gu_ws[rr * 16 + h];
  float sv[8], muv[8], rsvv[8];
  float m = -1e30f;
#pragma unroll
  for (int k = 0; k < 8; k++) {
    int j = jl + k * 16;
    size_t idx = ((size_t)rr * 128 + j) * 16 + h;
    float sxv = sxp0[rr * 128 + j] + sxp1[rr * 128 + j];
    float sqv = sqp0[rr * 128 + j] + sqp1[rr * 128 + j];
    float mu = sxv * (1.f / 1024.f);
    float rsv = rsqrtf(fmaxf(sqv * (1.f / 1024.f) - mu * mu, 0.f) + 1e-5f);
    float accv = sraw0[idx] + sraw1[idx];
    sv[k] = S0v + rsv * (accv - mu * Gv);
    muv[k] = mu; rsvv[k] = rsv;
    m = fmaxf(m, sv[k]);
  }
#pragma unroll
  for (int mk = 8; mk >= 1; mk >>= 1) m = fmaxf(m, __shfl_xor(m, mk, 16));
  float z = 0.f, c1 = 0.f;
#pragma unroll
  for (int k = 0; k < 8; k++) {
    int j = jl + k * 16;
    float p = expf(sv[k] - m);
    z += p;
    float p2 = p * rsvv[k];
    c1 += p2 * muv[k];
    s_ws[((size_t)rr * 128 + j) * 16 + h] = p2;
  }
#pragma unroll
  for (int mk = 8; mk >= 1; mk >>= 1) { z += __shfl_xor(z, mk, 16); c1 += __shfl_xor(c1, mk, 16); }
  if (jl == 0) {
    M_ws[rr * 16 + h] = m; Z_ws[rr * 16 + h] = z; C1_ws[rr * 16 + h] = c1;
  }
}

// ---------------------------------------------------------------------------
// K7: w_t[rr][e][h] = g_e*(sum_j p2[j,h]*x[j,e] - C1[h]) + b_e*Z[h]
// grid (8 es, 256 rr) = 2048 blocks, 128 thr. (unchanged from R14)
__global__ __launch_bounds__(128) void k_wun(
    const float* __restrict__ rpe, const float* __restrict__ lng, const float* __restrict__ lnb,
    const float* __restrict__ p2_ws,
    const float* __restrict__ Z_ws, const float* __restrict__ C1_ws,
    float* __restrict__ w_ws)
{
  __shared__ float xs[16][128];   // 8 KB
  __shared__ float p2s[128][16];  // 8 KB
  __shared__ float C1S[16], ZS[16];
  int es = blockIdx.x, rr = blockIdx.y, tid = threadIdx.x;
  int e0 = es * 128;
#pragma unroll
  for (int it = 0; it < 4; it++) {
    int f = it * 128 + tid;       // 512 float4s of p2
    int jj = f >> 2, hh = f & 3;
    *(float4*)&p2s[jj][hh * 4] = *(const float4*)(p2_ws + ((size_t)rr * 128 + jj) * 16 + hh * 4);
  }
  if (tid < 16) { C1S[tid] = C1_ws[rr * 16 + tid]; ZS[tid] = Z_ws[rr * 16 + tid]; }
  float acc[16];
#pragma unroll
  for (int h = 0; h < 16; h++) acc[h] = 0.f;

#define WUN_ROW(xval) \
  acc[0] += (xval) * p0.x;  acc[1] += (xval) * p0.y;  \
  acc[2] += (xval) * p0.z;  acc[3] += (xval) * p0.w;  \
  acc[4] += (xval) * p1.x;  acc[5] += (xval) * p1.y;  \
  acc[6] += (xval) * p1.z;  acc[7] += (xval) * p1.w;  \
  acc[8] += (xval) * p2v.x; acc[9] += (xval) * p2v.y; \
  acc[10] += (xval) * p2v.z; acc[11] += (xval) * p2v.w; \
  acc[12] += (xval) * p3.x; acc[13] += (xval) * p3.y; \
  acc[14] += (xval) * p3.z; acc[15] += (xval) * p3.w;

  for (int jc = 0; jc < 8; jc++) {
    __syncthreads();
#pragma unroll
    for (int it = 0; it < 4; it++) {
      int f = it * 128 + tid;     // 512 float4s: 16 rows x 128 e
      int row = f >> 5, e4 = f & 31;
      *(float4*)&xs[row][e4 * 4] =
          *(const float4*)(rpe + ((size_t)(rr * 128 + jc * 16 + row)) * 1024 + e0 + e4 * 4);
    }
    __syncthreads();
#pragma unroll
    for (int j = 0; j < 16; j++) {
      int jj = jc * 16 + j;
      float x = xs[j][tid];
      float4 p0 = *(float4*)&p2s[jj][0];
      float4 p1 = *(float4*)&p2s[jj][4];
      float4 p2v = *(float4*)&p2s[jj][8];
      float4 p3 = *(float4*)&p2s[jj][12];
      WUN_ROW(x)
    }
  }
#undef WUN_ROW

  int e = e0 + tid;
  float ge = lng[e], be = lnb[e];
  float* wp = w_ws + ((size_t)rr * 1024 + e) * 16;
#pragma unroll
  for (int hh = 0; hh < 4; hh++) {
    float4 o;
    o.x = ge * (acc[hh * 4 + 0] - C1S[hh * 4 + 0]) + be * ZS[hh * 4 + 0];
    o.y = ge * (acc[hh * 4 + 1] - C1S[hh * 4 + 1]) + be * ZS[hh * 4 + 1];
    o.z = ge * (acc[hh * 4 + 2] - C1S[hh * 4 + 2]) + be * ZS[hh * 4 + 2];
    o.w = ge * (acc[hh * 4 + 3] - C1S[hh * 4 + 3]) + be * ZS[hh * 4 + 3];
    *(float4*)(wp + hh * 4) = o;
  }
}

// ---------------------------------------------------------------------------
// K8: qv[rr][(g*2+hh)*64+d] += sum_e w_t[rr][e][g*2+hh]*Wrv[e][g*64+d]
// grid (8 g, 16 rrt, 8 es) = 1024 blocks, 256 thr. K=128, Wrv prefetched.
__global__ __launch_bounds__(256) void k_qv(
    const float* __restrict__ w_ws, const float* __restrict__ Wrv,
    float* __restrict__ qv_ws)
{
  __shared__ float As[32][133];  // [m][e] 17 KB, 133 pad -> conflict-free
  int g = blockIdx.x, rrt = blockIdx.y, es = blockIdx.z, tid = threadIdx.x;
  int rr0 = rrt * 16, e0 = es * 128;
  for (int f = tid; f < 2048; f += 256) {
    int rl = f >> 7, e = f & 127;
    float2 w2 = *(const float2*)(w_ws + ((size_t)(rr0 + rl) * 1024 + e0 + e) * 16 + g * 2);
    As[rl * 2 + 0][e] = w2.x;
    As[rl * 2 + 1][e] = w2.y;
  }
  __syncthreads();
  int cl = tid & 15, ms = tid >> 4;   // cols cl*4..+3, rows m=ms*2, ms*2+1
  const float* wp = Wrv + (size_t)e0 * 512 + g * 64 + cl * 4;
  float acc[2][4];
#pragma unroll
  for (int hh = 0; hh < 2; hh++)
#pragma unroll
    for (int s = 0; s < 4; s++) acc[hh][s] = 0.f;
  float4 wc = *(const float4*)wp;
  for (int e = 0; e < 128; e++) {
    int en = e + 1 < 128 ? e + 1 : 127;
    float4 wn = *(const float4*)(wp + (size_t)en * 512);
    float a0 = As[ms * 2][e], a1 = As[ms * 2 + 1][e];
    acc[0][0] += a0 * wc.x; acc[0][1] += a0 * wc.y; acc[0][2] += a0 * wc.z; acc[0][3] += a0 * wc.w;
    acc[1][0] += a1 * wc.x; acc[1][1] += a1 * wc.y; acc[1][2] += a1 * wc.z; acc[1][3] += a1 * wc.w;
    wc = wn;
  }
  int rr = rr0 + ms;
#pragma unroll
  for (int hh = 0; hh < 2; hh++) {
    float* qp = qv_ws + (size_t)rr * 1024 + (g * 2 + hh) * 64 + cl * 4;
#pragma unroll
    for (int s = 0; s < 4; s++) atomicAdd(qp + s, acc[hh][s]);
  }
}

// ---------------------------------------------------------------------------
// K9: out += qveff @ Wo, with k_comb folded into the prologue:
// per block, recompute mg/zg for its b (16-lane shfl reduce over M/Z, L2-hot)
// then sc[r][h] in LDS. qveff[r][e] = sc*(Z*(v+brv) + qv_ws).
// grid (4 ct, 32 rt, 8 es) = 1024 blocks, 256 thr.
__global__ __launch_bounds__(256) void k_out(
    const float* __restrict__ qv_ws, const float* __restrict__ v_ws,
    const float* __restrict__ brv, const float* __restrict__ Z_ws,
    const float* __restrict__ M_ws, const float* __restrict__ Wo,
    float* __restrict__ out)
{
  __shared__ float xs[8][128];  // 4 KB
  __shared__ float scl[8][16];  // 512 B
  int ct = blockIdx.x, rt = blockIdx.y, es = blockIdx.z, tid = threadIdx.x;
  int row0 = rt * 8, e0 = es * 128, c0 = ct * 256;
  // --- folded k_comb: mg/zg per h for this block's b ---
  {
    int h = tid >> 4, il = tid & 15;
    int b = row0 >> 7;
    float ml[8];
    float mg = -1e30f;
#pragma unroll
    for (int k = 0; k < 8; k++) {
      int i = il + k * 16;
      ml[k] = M_ws[((b << 7) + i) * 16 + h];
      mg = fmaxf(mg, ml[k]);
    }
#pragma unroll
    for (int mk = 8; mk >= 1; mk >>= 1) mg = fmaxf(mg, __shfl_xor(mg, mk, 16));
    float zg = 0.f;
#pragma unroll
    for (int k = 0; k < 8; k++) {
      int i = il + k * 16;
      zg += Z_ws[((b << 7) + i) * 16 + h] * expf(ml[k] - mg);
    }
#pragma unroll
    for (int mk = 8; mk >= 1; mk >>= 1) zg += __shfl_xor(zg, mk, 16);
    if (il < 8) {
      int row = row0 + il;
      scl[il][h] = expf(M_ws[(size_t)row * 16 + h] - mg) / zg;
    }
  }
  __syncthreads();
  for (int f = tid; f < 1024; f += 256) {
    int r = f >> 7, ei = f & 127;
    int e = e0 + ei, row = row0 + r;
    int h = e >> 6, gg = h >> 1, dl = e & 63;
    float vb = v_ws[row * 512 + gg * 64 + dl] + brv[gg * 64 + dl];
    xs[r][ei] = scl[r][h] * (Z_ws[row * 16 + h] * vb + qv_ws[(size_t)row * 1024 + e]);
  }
  __syncthreads();
  int cg = tid & 63, rs = tid >> 6;
  int c = c0 + cg * 4;
  const float* wp = Wo + (size_t)e0 * 1024 + c;
  float a0[4] = {0, 0, 0, 0}, a1[4] = {0, 0, 0, 0};
  float4 wc = *(const float4*)wp;
  for (int e = 0; e < 128; e++) {
    int en = e + 1 < 128 ? e + 1 : 127;
    float4 wn = *(const float4*)(wp + (size_t)en * 1024);
    float x0 = xs[rs][e], x1 = xs[rs + 4][e];
    a0[0] += x0 * wc.x; a0[1] += x0 * wc.y; a0[2] += x0 * wc.z; a0[3] += x0 * wc.w;
    a1[0] += x1 * wc.x; a1[1] += x1 * wc.y; a1[2] += x1 * wc.z; a1[3] += x1 * wc.w;
    wc = wn;
  }
#pragma unroll
  for (int s = 0; s < 4; s++) {
    atomicAdd(out + (size_t)(row0 + rs) * 1024 + c + s, a0[s]);
    atomicAdd(out + (size_t)(row0 + rs + 4) * 1024 + c + s, a1[s]);
  }
}

// ---------------------------------------------------------------------------
extern "C" void kernel_launch(void* const* d_in, const int* in_sizes, int n_in,
                              void* d_out, int out_size, void* d_ws, size_t ws_size,
                              hipStream_t stream) {
  (void)in_sizes; (void)n_in; (void)out_size; (void)ws_size;
  const float* Q   = (const float*)d_in[0];
  const float* K   = (const float*)d_in[1];
  const float* V   = (const float*)d_in[2];
  const float* rpe = (const float*)d_in[3];
  const float* lng = (const float*)d_in[4];
  const float* lnb = (const float*)d_in[5];
  const float* Wq  = (const float*)d_in[6];
  const float* bq  = (const float*)d_in[7];
  const float* Wk  = (const float*)d_in[8];
  const float* bk  = (const float*)d_in[9];
  const float* Wv  = (const float*)d_in[10];
  const float* bv  = (const float*)d_in[11];
  const float* Wrk = (const float*)d_in[12];
  const float* brk = (const float*)d_in[13];
  const float* Wrv = (const float*)d_in[14];
  const float* brv = (const float*)d_in[15];
  const float* Wo  = (const float*)d_in[16];
  const float* bo  = (const float*)d_in[17];
  float* out = (float*)d_out;

  float* ws    = (float*)d_ws;
  float* q_ws  = ws;                    // 262144
  float* k_ws  = q_ws + 262144;         // 131072
  float* v_ws  = k_ws + 131072;         // 131072
  float* ut_ws = v_ws + 131072;         // 4194304  (reused as w_ws after k_dotp)
  float* S0_ws = ut_ws + 4194304;       // 4096  (Bu only; base dot inline in k_attn_p)
  float* Gu_ws = S0_ws + 4096;          // 4096
  float* s_ws  = Gu_ws + 4096;          // 524288   (p2)
  float* mu_ws = s_ws + 524288;         // 32768 (unused, layout keep)
  float* rs_ws = mu_ws + 32768;         // 32768 (unused)
  float* M_ws  = rs_ws + 32768;         // 4096
  float* Z_ws  = M_ws + 4096;           // 4096
  float* C1_ws = Z_ws + 4096;           // 4096
  float* sc_ws = C1_ws + 4096;          // 4096 (unused, layout keep)
  float* qv_ws = sc_ws + 4096;          // 262144
  float* sraw0 = qv_ws + 262144;        // 524288
  float* sraw1 = sraw0 + 524288;        // 524288
  float* sxp0  = sraw1 + 524288;        // 32768
  float* sxp1  = sxp0 + 32768;          // 32768
  float* sqp0  = sxp1 + 32768;          // 32768
  float* sqp1  = sqp0 + 32768;          // 32768  (~28 MB total)
  float* w_ws  = ut_ws;                 // reuse

  k_zero<<<256, 256, 0, stream>>>(bq, bk, bv, bo, q_ws, k_ws, v_ws, qv_ws, out, Gu_ws, S0_ws);
  k_qkv<<<dim3(8, 32, 4), 256, 0, stream>>>(Q, K, V, Wq, Wk, Wv, q_ws, k_ws, v_ws);
  k_uproj<<<dim3(8, 16, 8), 256, 0, stream>>>(q_ws, Wrk, lng, lnb, ut_ws, Gu_ws, S0_ws);
  k_dotp<<<dim3(4, 256, 2), 128, 0, stream>>>(rpe, lng, ut_ws,
                                              sraw0, sraw1, sxp0, sxp1, sqp0, sqp1);
  k_attn_p<<<256, 256, 0, stream>>>(sraw0, sraw1, sxp0, sxp1, sqp0, sqp1,
                                    q_ws, k_ws, brk, Gu_ws, S0_ws,
                                    s_ws, M_ws, Z_ws, C1_ws);
  k_wun<<<dim3(8, 256), 128, 0, stream>>>(rpe, lng, lnb, s_ws, Z_ws, C1_ws, w_ws);
  k_qv<<<dim3(8, 16, 8), 256, 0, stream>>>(w_ws, Wrv, qv_ws);
  k_out<<<dim3(4, 32, 8), 256, 0, stream>>>(qv_ws, v_ws, brv, Z_ws, M_ws, Wo, out);
}